// Round 1
// baseline (1391.163 us; speedup 1.0000x reference)
//
#include <hip/hip_runtime.h>
#include <cmath>

// Problem dims (fixed)
#define CB 128   // B
#define CL 50    // L
#define CN 12    // N == N2 == M
#define CS 20    // S
#define CM 12    // M
#define CD 100   // D
#define TB 128   // block size (2 waves)

// ---------------------------------------------------------------------------
// Generic neighbor attention: per group g
//   x[n][d] = ctx[g][d] * nbr[g][n][d]
//   y[n][j] = leaky( sum_d x[n][d] * W1[d][j] )
//   score[n] = sum_j y[n][j] * w2[j]
//   att = softmax_n(score)
//   out[g][d] = (l2norm of) sum_n att[n] * nbr[g][n][d]
// ---------------------------------------------------------------------------
__global__ __launch_bounds__(TB) void neigh_att_kernel(
    const float* __restrict__ ctx,   // [G, D]
    const float* __restrict__ nbr,   // [G, CN, D]
    const float* __restrict__ W1,    // [D, D]
    const float* __restrict__ w2,    // [D]
    float* __restrict__ outp,        // [G, D]
    int do_l2)
{
    const int g = blockIdx.x;
    const int t = threadIdx.x;
    __shared__ float s_ctx[CD];
    __shared__ float s_nbr[CN][CD];
    __shared__ float s_x[CN][CD];
    __shared__ float s_red[CN][TB];
    __shared__ float s_att[CN];
    __shared__ float s_tot[CD];
    __shared__ float s_rn;

    const float* gc = ctx + (size_t)g * CD;
    const float* gn = nbr + (size_t)g * (CN * CD);
    for (int d = t; d < CD; d += TB) s_ctx[d] = gc[d];
    __syncthreads();
    for (int i = t; i < CN * CD; i += TB) {
        int n = i / CD, d = i - n * CD;
        float v = gn[i];
        s_nbr[n][d] = v;
        s_x[n][d] = v * s_ctx[d];
    }
    __syncthreads();

    float sc[CN];
#pragma unroll
    for (int n = 0; n < CN; ++n) sc[n] = 0.f;
    if (t < CD) {
        float acc[CN];
#pragma unroll
        for (int n = 0; n < CN; ++n) acc[n] = 0.f;
        for (int d0 = 0; d0 < CD; d0 += 4) {
            float4 xv[CN];
#pragma unroll
            for (int n = 0; n < CN; ++n) xv[n] = *(const float4*)&s_x[n][d0];
#pragma unroll
            for (int dd = 0; dd < 4; ++dd) {
                float w = W1[(d0 + dd) * CD + t];
#pragma unroll
                for (int n = 0; n < CN; ++n) {
                    float xnd = (dd == 0) ? xv[n].x : (dd == 1) ? xv[n].y
                              : (dd == 2) ? xv[n].z : xv[n].w;
                    acc[n] = fmaf(xnd, w, acc[n]);
                }
            }
        }
        float w2v = w2[t];
#pragma unroll
        for (int n = 0; n < CN; ++n) {
            float y = acc[n];
            y = (y >= 0.f) ? y : 0.2f * y;   // leaky_relu, slope 0.2
            sc[n] = y * w2v;
        }
    }
#pragma unroll
    for (int n = 0; n < CN; ++n) s_red[n][t] = sc[n];
    __syncthreads();
    for (int stride = TB / 2; stride > 0; stride >>= 1) {
        if (t < stride) {
#pragma unroll
            for (int n = 0; n < CN; ++n) s_red[n][t] += s_red[n][t + stride];
        }
        __syncthreads();
    }
    if (t == 0) {
        float m = -1e30f;
#pragma unroll
        for (int n = 0; n < CN; ++n) m = fmaxf(m, s_red[n][0]);
        float e[CN];
        float ssum = 0.f;
#pragma unroll
        for (int n = 0; n < CN; ++n) { e[n] = expf(s_red[n][0] - m); ssum += e[n]; }
        float inv = 1.f / ssum;
#pragma unroll
        for (int n = 0; n < CN; ++n) s_att[n] = e[n] * inv;
    }
    __syncthreads();
    if (t < CD) {
        float tot = 0.f;
#pragma unroll
        for (int n = 0; n < CN; ++n) tot = fmaf(s_att[n], s_nbr[n][t], tot);
        s_tot[t] = tot;
    }
    __syncthreads();
    if (do_l2) {
        if (t < 64) {
            float sq = 0.f;
            for (int d = t; d < CD; d += 64) sq += s_tot[d] * s_tot[d];
#pragma unroll
            for (int off = 32; off > 0; off >>= 1) sq += __shfl_down(sq, off, 64);
            if (t == 0) s_rn = 1.f / fmaxf(sqrtf(sq), 1e-12f);
        }
        __syncthreads();
        if (t < CD) outp[(size_t)g * CD + t] = s_tot[t] * s_rn;
    } else {
        if (t < CD) outp[(size_t)g * CD + t] = s_tot[t];
    }
}

// ---------------------------------------------------------------------------
// Target neighbor attention: per group g = b*S+s
//   xa[m][d] = t[d]*tn[m][d]; xb[m][d] = sl[d]+tn[m][d]  (cat = [xa, xb])
//   y[m][j] = tanh( sum_d xa*W3[d][j] + xb*W3[D+d][j] )
//   score[m] = sum_j y[m][j]*w4[j]; att = softmax_m
//   out = l2norm( (sum_m att[m]*tn[m] + tar0) * 0.5 )
// ---------------------------------------------------------------------------
__global__ __launch_bounds__(TB) void tar_att_kernel(
    const float* __restrict__ tvec,  // [B*S, D]
    const float* __restrict__ sl,    // row per b: sl + b*slStride  (l=0 slice)
    const float* __restrict__ tn,    // [B*S, CM, D]
    const float* __restrict__ W3,    // [2D, D]
    const float* __restrict__ w4,    // [D]
    const float* __restrict__ tar0,  // [B*S, D]
    float* __restrict__ outp,        // [B*S, D]
    int slStride)
{
    const int g = blockIdx.x;
    const int b = g / CS;
    const int t = threadIdx.x;
    __shared__ float s_t[CD], s_sl[CD];
    __shared__ float s_tn[CM][CD], s_xa[CM][CD], s_xb[CM][CD];
    __shared__ float s_red[CM][TB];
    __shared__ float s_att[CM];
    __shared__ float s_tot[CD];
    __shared__ float s_rn;

    for (int d = t; d < CD; d += TB) {
        s_t[d] = tvec[(size_t)g * CD + d];
        s_sl[d] = sl[(size_t)b * slStride + d];
    }
    __syncthreads();
    for (int i = t; i < CM * CD; i += TB) {
        int m = i / CD, d = i - m * CD;
        float v = tn[(size_t)g * (CM * CD) + i];
        s_tn[m][d] = v;
        s_xa[m][d] = v * s_t[d];
        s_xb[m][d] = v + s_sl[d];
    }
    __syncthreads();

    float sc[CM];
#pragma unroll
    for (int m = 0; m < CM; ++m) sc[m] = 0.f;
    if (t < CD) {
        float acc[CM];
#pragma unroll
        for (int m = 0; m < CM; ++m) acc[m] = 0.f;
        for (int d = 0; d < CD; ++d) {
            float wa = W3[d * CD + t];
            float wb = W3[(CD + d) * CD + t];
#pragma unroll
            for (int m = 0; m < CM; ++m)
                acc[m] = fmaf(s_xa[m][d], wa, fmaf(s_xb[m][d], wb, acc[m]));
        }
        float w4v = w4[t];
#pragma unroll
        for (int m = 0; m < CM; ++m) sc[m] = tanhf(acc[m]) * w4v;
    }
#pragma unroll
    for (int m = 0; m < CM; ++m) s_red[m][t] = sc[m];
    __syncthreads();
    for (int stride = TB / 2; stride > 0; stride >>= 1) {
        if (t < stride) {
#pragma unroll
            for (int m = 0; m < CM; ++m) s_red[m][t] += s_red[m][t + stride];
        }
        __syncthreads();
    }
    if (t == 0) {
        float mx = -1e30f;
#pragma unroll
        for (int m = 0; m < CM; ++m) mx = fmaxf(mx, s_red[m][0]);
        float e[CM];
        float ssum = 0.f;
#pragma unroll
        for (int m = 0; m < CM; ++m) { e[m] = expf(s_red[m][0] - mx); ssum += e[m]; }
        float inv = 1.f / ssum;
#pragma unroll
        for (int m = 0; m < CM; ++m) s_att[m] = e[m] * inv;
    }
    __syncthreads();
    if (t < CD) {
        float tot = 0.f;
#pragma unroll
        for (int m = 0; m < CM; ++m) tot = fmaf(s_att[m], s_tn[m][t], tot);
        tot = (tot + tar0[(size_t)g * CD + t]) * 0.5f;
        s_tot[t] = tot;
    }
    __syncthreads();
    if (t < 64) {
        float sq = 0.f;
        for (int d = t; d < CD; d += 64) sq += s_tot[d] * s_tot[d];
#pragma unroll
        for (int off = 32; off > 0; off >>= 1) sq += __shfl_down(sq, off, 64);
        if (t == 0) s_rn = 1.f / fmaxf(sqrtf(sq), 1e-12f);
    }
    __syncthreads();
    if (t < CD) outp[(size_t)g * CD + t] = s_tot[t] * s_rn;
}

// ---------------------------------------------------------------------------
// Output assembly.
// out0 = stack([bcastS(sess_self), bcastS(emb0), bcastS(emb1)]) : [3,B,S,L,D]
// out1 = stack([T0,T1,T0,T1,T2, T0,T1,T0,T1,T2])                : [10,B,S,D]
// ---------------------------------------------------------------------------
__global__ void assemble_kernel(
    const float* __restrict__ sess_self, const float* __restrict__ emb0,
    const float* __restrict__ emb1, const float* __restrict__ tar_self,
    const float* __restrict__ T1, const float* __restrict__ T2,
    float4* __restrict__ out)
{
    const int LD4 = CL * CD / 4;          // 1250
    const int SLD4 = CS * LD4;            // 25000
    const int LAY0 = CB * SLD4;           // 3,200,000 float4 per sess layer
    const int TOT0 = 3 * LAY0;            // 9,600,000
    const int LAY1 = CB * CS * CD / 4;    // 64,000 float4 per tar layer
    const int TOT = TOT0 + 10 * LAY1;     // 10,240,000

    for (int i = blockIdx.x * blockDim.x + threadIdx.x; i < TOT;
         i += gridDim.x * blockDim.x) {
        float4 v;
        if (i < TOT0) {
            int layer = i / LAY0;
            int r = i - layer * LAY0;
            int b = r / SLD4;
            int r2 = r - b * SLD4;
            int ld4 = r2 % LD4;           // s index is irrelevant (S-broadcast)
            const float* src = (layer == 0) ? sess_self : (layer == 1) ? emb0 : emb1;
            v = ((const float4*)src)[b * LD4 + ld4];
        } else {
            int j = i - TOT0;
            int layer = j / LAY1;
            int r = j - layer * LAY1;
            int k = layer % 5;            // [T0,T1,T0,T1,T2] repeated
            const float* src = (k == 4) ? T2 : ((k == 1) || (k == 3)) ? T1 : tar_self;
            v = ((const float4*)src)[r];
        }
        out[i] = v;
    }
}

extern "C" void kernel_launch(void* const* d_in, const int* in_sizes, int n_in,
                              void* d_out, int out_size, void* d_ws, size_t ws_size,
                              hipStream_t stream)
{
    const float* sess_self     = (const float*)d_in[0];
    const float* sess_neighbor = (const float*)d_in[1];
    const float* sess_neighbor2= (const float*)d_in[2];
    const float* tar_self      = (const float*)d_in[3];
    const float* tar_neighbor  = (const float*)d_in[4];
    const float* w1            = (const float*)d_in[5];  // [2, D, D]
    const float* w2            = (const float*)d_in[6];  // [2, D, 1]
    const float* w3            = (const float*)d_in[7];  // [2, 2D, D]
    const float* w4            = (const float*)d_in[8];  // [2, D, 1]
    // d_in[9] = session_len (unused by reference forward)
    float* out = (float*)d_out;
    float* ws  = (float*)d_ws;

    // workspace layout (floats): total 9,472,000 floats = 37.9 MB
    float* emb0 = ws;                    // [B*L, D]     640,000
    float* emb1 = ws + 640000;           // [B*L, D]     640,000
    float* sn1  = ws + 1280000;          // [B*L*N, D] 7,680,000
    float* T1   = ws + 8960000;          // [B*S, D]     256,000
    float* T2   = ws + 9216000;          // [B*S, D]     256,000

    // layer 0 session attention: ctx = sess_self (mean over S-broadcast == itself)
    neigh_att_kernel<<<CB * CL, TB, 0, stream>>>(
        sess_self, sess_neighbor, w1, w2, emb0, 1);
    // 2-hop aggregation (layer 0 weights): groups = (b,l,n)
    neigh_att_kernel<<<CB * CL * CN, TB, 0, stream>>>(
        sess_neighbor, sess_neighbor2, w1, w2, sn1, 0);
    // layer 1 session attention: ctx = emb0, nbr = sn1, layer-1 weights
    neigh_att_kernel<<<CB * CL, TB, 0, stream>>>(
        emb0, sn1, w1 + CD * CD, w2 + CD, emb1, 1);
    // target attention layer 0: t = tar_self, sess_last = emb0[b, l=0, :]
    tar_att_kernel<<<CB * CS, TB, 0, stream>>>(
        tar_self, emb0, tar_neighbor, w3, w4, tar_self, T1, CL * CD);
    // target attention layer 1: t = T1, sess_last = sess_self[b, 0, :]
    tar_att_kernel<<<CB * CS, TB, 0, stream>>>(
        T1, sess_self, tar_neighbor, w3 + 2 * CD * CD, w4 + CD, tar_self, T2, CL * CD);
    // write both stacked outputs
    assemble_kernel<<<2048, 256, 0, stream>>>(
        sess_self, emb0, emb1, tar_self, T1, T2, (float4*)out);
}

// Round 2
// 499.089 us; speedup vs baseline: 2.7874x; 2.7874x over previous
//
#include <hip/hip_runtime.h>
#include <cmath>

// Problem dims (fixed)
#define CB 128   // B
#define CL 50    // L
#define CN 12    // N == N2 == M
#define CS 20    // S
#define CM 12    // M
#define CD 100   // D

typedef __attribute__((ext_vector_type(8))) short short8;
typedef __attribute__((ext_vector_type(4))) float f32x4;

__device__ __forceinline__ unsigned short f2bf(float f) {
    unsigned int u = __float_as_uint(f);
    u += 0x7FFFu + ((u >> 16) & 1u);     // round-to-nearest-even
    return (unsigned short)(u >> 16);
}
__device__ __forceinline__ float4 mul4(float4 a, float4 b) {
    return make_float4(a.x * b.x, a.y * b.y, a.z * b.z, a.w * b.w);
}
__device__ __forceinline__ float4 add4(float4 a, float4 b) {
    return make_float4(a.x + b.x, a.y + b.y, a.z + b.z, a.w + b.w);
}
__device__ __forceinline__ short8 pack8(float4 a, float4 b) {
    short8 v;
    v[0] = (short)f2bf(a.x); v[1] = (short)f2bf(a.y);
    v[2] = (short)f2bf(a.z); v[3] = (short)f2bf(a.w);
    v[4] = (short)f2bf(b.x); v[5] = (short)f2bf(b.y);
    v[6] = (short)f2bf(b.z); v[7] = (short)f2bf(b.w);
    return v;
}

// ---------------------------------------------------------------------------
// Weight prep: transpose + pad + bf16-convert.
//   w1t[l][n][k] : n<112, k<128,  = w1[l][k][n] (valid n<100,k<100 else 0)
//   w3t[l][n][k] : n<112, k<224,  = w3[l][k][n] (valid n<100,k<200 else 0)
// ---------------------------------------------------------------------------
__global__ void prep_weights_kernel(const float* __restrict__ w1,
                                    const float* __restrict__ w3,
                                    unsigned short* __restrict__ w1t,
                                    unsigned short* __restrict__ w3t)
{
    int idx = blockIdx.x * 256 + threadIdx.x;
    const int TOT1 = 2 * 112 * 128;   // 28672
    const int TOT3 = 2 * 112 * 224;   // 50176
    if (idx < TOT1) {
        int l = idx / (112 * 128);
        int r = idx - l * (112 * 128);
        int n = r / 128, k = r - (r / 128) * 128;
        float v = (n < CD && k < CD) ? w1[l * CD * CD + k * CD + n] : 0.f;
        w1t[idx] = f2bf(v);
    } else if (idx < TOT1 + TOT3) {
        int j = idx - TOT1;
        int l = j / (112 * 224);
        int r = j - l * (112 * 224);
        int n = r / 224, k = r - (r / 224) * 224;
        float v = (n < CD && k < 2 * CD) ? w3[l * 2 * CD * CD + k * CD + n] : 0.f;
        w3t[j] = f2bf(v);
    }
}

// ---------------------------------------------------------------------------
// Fused neighbor attention via MFMA. 8 groups (=128 padded rows) per block.
//   x[r][k] = a[g][k] * c[g][n][k]  (bf16, K padded 100->128)
//   y = x @ W1 (via w1t),  score[r] = sum_j leaky(y[r][j]) * w2[j]
//   att = softmax over n<12 per group; out[g][d] = sum_n att*c  (opt l2norm)
// ---------------------------------------------------------------------------
template<int DO_L2>
__global__ __launch_bounds__(256) void neigh_mfma_kernel(
    const float* __restrict__ a_ptr,          // [G, 100]
    const float* __restrict__ c_ptr,          // [G, 12, 100]
    const unsigned short* __restrict__ w1t,   // [112][128] bf16
    const float* __restrict__ w2,             // [100]
    float* __restrict__ outp,                 // [G, 100]
    int G)
{
    __shared__ __align__(16) unsigned short sA[128 * 128];  // 32 KB, stride 256B
    __shared__ __align__(16) unsigned short sB[112 * 128];  // 28 KB, stride 256B
    __shared__ float s_score[128];
    __shared__ float s_att[96];
    __shared__ float s_sq[8][25];
    __shared__ float s_rn[8];

    const int tid = threadIdx.x;
    const int g0 = blockIdx.x * 8;

    // ---- stage A (ctx * nbr -> bf16, swizzled) ----
    for (int i = tid; i < 2048; i += 256) {           // 128 rows x 16 chunks
        int row = i >> 4, kc = i & 15;
        int k0 = kc * 8;
        int gl = row >> 4, n = row & 15;
        int nl = (n < CN) ? n : 0;                    // clamp pad rows (scores unused)
        const float* cp = c_ptr + ((size_t)(g0 + gl) * CN + nl) * CD;
        const float* ap = a_ptr + (size_t)(g0 + gl) * CD;
        short8 v;
        if (k0 < 96) {
            float4 c0 = *(const float4*)(cp + k0);
            float4 c1 = *(const float4*)(cp + k0 + 4);
            float4 a0 = *(const float4*)(ap + k0);
            float4 a1 = *(const float4*)(ap + k0 + 4);
            v = pack8(mul4(a0, c0), mul4(a1, c1));
        } else if (k0 == 96) {
            float4 c0 = *(const float4*)(cp + 96);
            float4 a0 = *(const float4*)(ap + 96);
            float4 z = make_float4(0.f, 0.f, 0.f, 0.f);
            v = pack8(mul4(a0, c0), z);
        } else {
            float4 z = make_float4(0.f, 0.f, 0.f, 0.f);
            v = pack8(z, z);
        }
        char* dst = (char*)sA + row * 256 + ((k0 * 2) ^ ((row & 7) << 4));
        *(short8*)dst = v;
    }
    // ---- stage B (w1t, swizzled) ----
    for (int i = tid; i < 1792; i += 256) {           // 112 rows x 16 chunks
        int n = i >> 4, kc = i & 15;
        short8 v = *(const short8*)(w1t + n * 128 + kc * 8);
        char* dst = (char*)sB + n * 256 + ((kc * 16) ^ ((n & 7) << 4));
        *(short8*)dst = v;
    }
    __syncthreads();

    // ---- MFMA: rows per wave = 32 (2 row-tiles), cols = 112 (7 tiles) ----
    const int wave = tid >> 6, lane = tid & 63;
    const int lhi = lane >> 4, llo = lane & 15;
    f32x4 acc[2][7];
#pragma unroll
    for (int mt = 0; mt < 2; ++mt)
#pragma unroll
        for (int nt = 0; nt < 7; ++nt)
            acc[mt][nt] = (f32x4){0.f, 0.f, 0.f, 0.f};

    const char* pA = (const char*)sA;
    const char* pB = (const char*)sB;
#pragma unroll
    for (int ks = 0; ks < 4; ++ks) {
        int kb = (ks * 32 + lhi * 8) * 2;             // byte offset in row
        short8 af[2], bf[7];
#pragma unroll
        for (int mt = 0; mt < 2; ++mt) {
            int row = wave * 32 + mt * 16 + llo;
            af[mt] = *(const short8*)(pA + row * 256 + (kb ^ ((row & 7) << 4)));
        }
#pragma unroll
        for (int nt = 0; nt < 7; ++nt) {
            int nr = nt * 16 + llo;
            bf[nt] = *(const short8*)(pB + nr * 256 + (kb ^ ((nr & 7) << 4)));
        }
#pragma unroll
        for (int mt = 0; mt < 2; ++mt)
#pragma unroll
            for (int nt = 0; nt < 7; ++nt)
                acc[mt][nt] = __builtin_amdgcn_mfma_f32_16x16x32_bf16(
                    af[mt], bf[nt], acc[mt][nt], 0, 0, 0);
    }

    // ---- scores: leaky + dot w2 + reduce over 16 col-lanes ----
    float w2v[7];
#pragma unroll
    for (int nt = 0; nt < 7; ++nt) {
        int n = nt * 16 + llo;
        w2v[nt] = (n < CD) ? w2[n] : 0.f;
    }
#pragma unroll
    for (int mt = 0; mt < 2; ++mt) {
        float s[4] = {0.f, 0.f, 0.f, 0.f};
#pragma unroll
        for (int nt = 0; nt < 7; ++nt)
#pragma unroll
            for (int r = 0; r < 4; ++r) {
                float y = acc[mt][nt][r];
                y = (y >= 0.f) ? y : 0.2f * y;
                s[r] = fmaf(y, w2v[nt], s[r]);
            }
#pragma unroll
        for (int off = 1; off < 16; off <<= 1)
#pragma unroll
            for (int r = 0; r < 4; ++r) s[r] += __shfl_xor(s[r], off, 64);
        if (llo == 0) {
            int rowb = wave * 32 + mt * 16 + lhi * 4;
#pragma unroll
            for (int r = 0; r < 4; ++r) s_score[rowb + r] = s[r];
        }
    }
    __syncthreads();

    // ---- per-group softmax over n<12 ----
    if (tid < 8) {
        float mx = -1e30f;
        for (int n = 0; n < CN; ++n) mx = fmaxf(mx, s_score[tid * 16 + n]);
        float e[CN], sum = 0.f;
        for (int n = 0; n < CN; ++n) { e[n] = expf(s_score[tid * 16 + n] - mx); sum += e[n]; }
        float inv = 1.f / sum;
        for (int n = 0; n < CN; ++n) s_att[tid * CN + n] = e[n] * inv;
    }
    __syncthreads();

    // ---- weighted sum (fp32 re-read, L2-hot) + optional l2norm + store ----
    const bool act = tid < 200;
    int gl = tid / 25, d4 = tid % 25;
    float4 tot = make_float4(0.f, 0.f, 0.f, 0.f);
    if (act) {
        const float* crow = c_ptr + (size_t)(g0 + gl) * CN * CD + d4 * 4;
#pragma unroll
        for (int n = 0; n < CN; ++n) {
            float4 cv = *(const float4*)(crow + n * CD);
            float at = s_att[gl * CN + n];
            tot.x = fmaf(at, cv.x, tot.x);
            tot.y = fmaf(at, cv.y, tot.y);
            tot.z = fmaf(at, cv.z, tot.z);
            tot.w = fmaf(at, cv.w, tot.w);
        }
    }
    if (DO_L2) {
        if (act) s_sq[gl][d4] = tot.x * tot.x + tot.y * tot.y + tot.z * tot.z + tot.w * tot.w;
        __syncthreads();
        if (tid < 8) {
            float sq = 0.f;
            for (int j = 0; j < 25; ++j) sq += s_sq[tid][j];
            s_rn[tid] = 1.f / fmaxf(sqrtf(sq), 1e-12f);
        }
        __syncthreads();
        if (act) {
            float rn = s_rn[gl];
            tot.x *= rn; tot.y *= rn; tot.z *= rn; tot.w *= rn;
        }
    }
    if (act) *(float4*)(outp + (size_t)(g0 + gl) * CD + d4 * 4) = tot;
}

// ---------------------------------------------------------------------------
// Fused target attention via MFMA. 8 groups per block, K = 200 padded to 224.
//   x[r][k<100] = t[g][k]*tn[g][m][k];  x[r][100+k'] = sl[b][k'] + tn[g][m][k']
//   y = x @ W3, score = sum_j tanh(y)*w4[j]; softmax over m<12
//   out = l2norm( (sum_m att*tn + tar0) * 0.5 )
// ---------------------------------------------------------------------------
__global__ __launch_bounds__(256) void tar_mfma_kernel(
    const float* __restrict__ tvec,           // [2560, 100]
    const float* __restrict__ sl,             // per-b row, stride slStride
    const float* __restrict__ tn,             // [2560, 12, 100]
    const unsigned short* __restrict__ w3t,   // [112][224] bf16
    const float* __restrict__ w4,             // [100]
    const float* __restrict__ tar0,           // [2560, 100]
    float* __restrict__ outp,                 // [2560, 100]
    int slStride)
{
    // physical row stride = 512 B (28 data chunks + pad so 3-bit XOR stays in-row)
    __shared__ __align__(16) unsigned short sA[128 * 256];  // 64 KB
    __shared__ __align__(16) unsigned short sB[112 * 256];  // 56 KB
    __shared__ float s_score[128];
    __shared__ float s_att[96];
    __shared__ float s_sq[8][25];
    __shared__ float s_rn[8];

    const int tid = threadIdx.x;
    const int g0 = blockIdx.x * 8;

    // ---- stage A ----
    for (int i = tid; i < 3584; i += 256) {           // 128 rows x 28 chunks
        int row = i / 28, kc = i - (i / 28) * 28;
        int k0 = kc * 8;
        int gl = row >> 4, m = row & 15;
        int ml = (m < CM) ? m : 0;
        int g = g0 + gl;
        int b = g / CS;
        const float* tnr = tn + ((size_t)g * CM + ml) * CD;
        float4 q[2];
#pragma unroll
        for (int h = 0; h < 2; ++h) {
            int k = k0 + h * 4;
            if (k < CD) {
                float4 tn4 = *(const float4*)(tnr + k);
                float4 t4 = *(const float4*)(tvec + (size_t)g * CD + k);
                q[h] = mul4(t4, tn4);
            } else if (k < 2 * CD) {
                int k2 = k - CD;
                float4 tn4 = *(const float4*)(tnr + k2);
                float4 sl4 = *(const float4*)(sl + (size_t)b * slStride + k2);
                q[h] = add4(sl4, tn4);
            } else {
                q[h] = make_float4(0.f, 0.f, 0.f, 0.f);
            }
        }
        char* dst = (char*)sA + row * 512 + ((k0 * 2) ^ ((row & 7) << 4));
        *(short8*)dst = pack8(q[0], q[1]);
    }
    // ---- stage B ----
    for (int i = tid; i < 3136; i += 256) {           // 112 rows x 28 chunks
        int n = i / 28, kc = i - (i / 28) * 28;
        short8 v = *(const short8*)(w3t + n * 224 + kc * 8);
        char* dst = (char*)sB + n * 512 + ((kc * 16) ^ ((n & 7) << 4));
        *(short8*)dst = v;
    }
    __syncthreads();

    const int wave = tid >> 6, lane = tid & 63;
    const int lhi = lane >> 4, llo = lane & 15;
    f32x4 acc[2][7];
#pragma unroll
    for (int mt = 0; mt < 2; ++mt)
#pragma unroll
        for (int nt = 0; nt < 7; ++nt)
            acc[mt][nt] = (f32x4){0.f, 0.f, 0.f, 0.f};

    const char* pA = (const char*)sA;
    const char* pB = (const char*)sB;
#pragma unroll
    for (int ks = 0; ks < 7; ++ks) {
        int kb = (ks * 32 + lhi * 8) * 2;
        short8 af[2], bf[7];
#pragma unroll
        for (int mt = 0; mt < 2; ++mt) {
            int row = wave * 32 + mt * 16 + llo;
            af[mt] = *(const short8*)(pA + row * 512 + (kb ^ ((row & 7) << 4)));
        }
#pragma unroll
        for (int nt = 0; nt < 7; ++nt) {
            int nr = nt * 16 + llo;
            bf[nt] = *(const short8*)(pB + nr * 512 + (kb ^ ((nr & 7) << 4)));
        }
#pragma unroll
        for (int mt = 0; mt < 2; ++mt)
#pragma unroll
            for (int nt = 0; nt < 7; ++nt)
                acc[mt][nt] = __builtin_amdgcn_mfma_f32_16x16x32_bf16(
                    af[mt], bf[nt], acc[mt][nt], 0, 0, 0);
    }

    float w4v[7];
#pragma unroll
    for (int nt = 0; nt < 7; ++nt) {
        int n = nt * 16 + llo;
        w4v[nt] = (n < CD) ? w4[n] : 0.f;
    }
#pragma unroll
    for (int mt = 0; mt < 2; ++mt) {
        float s[4] = {0.f, 0.f, 0.f, 0.f};
#pragma unroll
        for (int nt = 0; nt < 7; ++nt)
#pragma unroll
            for (int r = 0; r < 4; ++r)
                s[r] = fmaf(tanhf(acc[mt][nt][r]), w4v[nt], s[r]);
#pragma unroll
        for (int off = 1; off < 16; off <<= 1)
#pragma unroll
            for (int r = 0; r < 4; ++r) s[r] += __shfl_xor(s[r], off, 64);
        if (llo == 0) {
            int rowb = wave * 32 + mt * 16 + lhi * 4;
#pragma unroll
            for (int r = 0; r < 4; ++r) s_score[rowb + r] = s[r];
        }
    }
    __syncthreads();

    if (tid < 8) {
        float mx = -1e30f;
        for (int m = 0; m < CM; ++m) mx = fmaxf(mx, s_score[tid * 16 + m]);
        float e[CM], sum = 0.f;
        for (int m = 0; m < CM; ++m) { e[m] = expf(s_score[tid * 16 + m] - mx); sum += e[m]; }
        float inv = 1.f / sum;
        for (int m = 0; m < CM; ++m) s_att[tid * CM + m] = e[m] * inv;
    }
    __syncthreads();

    const bool act = tid < 200;
    int gl = tid / 25, d4 = tid % 25;
    float4 tot = make_float4(0.f, 0.f, 0.f, 0.f);
    if (act) {
        const float* tnr = tn + (size_t)(g0 + gl) * CM * CD + d4 * 4;
#pragma unroll
        for (int m = 0; m < CM; ++m) {
            float4 cv = *(const float4*)(tnr + m * CD);
            float at = s_att[gl * CM + m];
            tot.x = fmaf(at, cv.x, tot.x);
            tot.y = fmaf(at, cv.y, tot.y);
            tot.z = fmaf(at, cv.z, tot.z);
            tot.w = fmaf(at, cv.w, tot.w);
        }
        float4 t0 = *(const float4*)(tar0 + (size_t)(g0 + gl) * CD + d4 * 4);
        tot.x = (tot.x + t0.x) * 0.5f;
        tot.y = (tot.y + t0.y) * 0.5f;
        tot.z = (tot.z + t0.z) * 0.5f;
        tot.w = (tot.w + t0.w) * 0.5f;
        s_sq[gl][d4] = tot.x * tot.x + tot.y * tot.y + tot.z * tot.z + tot.w * tot.w;
    }
    __syncthreads();
    if (tid < 8) {
        float sq = 0.f;
        for (int j = 0; j < 25; ++j) sq += s_sq[tid][j];
        s_rn[tid] = 1.f / fmaxf(sqrtf(sq), 1e-12f);
    }
    __syncthreads();
    if (act) {
        float rn = s_rn[gl];
        tot.x *= rn; tot.y *= rn; tot.z *= rn; tot.w *= rn;
        *(float4*)(outp + (size_t)(g0 + gl) * CD + d4 * 4) = tot;
    }
}

// ---------------------------------------------------------------------------
// Output assembly (unchanged from round 1, verified).
// ---------------------------------------------------------------------------
__global__ void assemble_kernel(
    const float* __restrict__ sess_self, const float* __restrict__ emb0,
    const float* __restrict__ emb1, const float* __restrict__ tar_self,
    const float* __restrict__ T1, const float* __restrict__ T2,
    float4* __restrict__ out)
{
    const int LD4 = CL * CD / 4;          // 1250
    const int SLD4 = CS * LD4;            // 25000
    const int LAY0 = CB * SLD4;           // 3,200,000
    const int TOT0 = 3 * LAY0;            // 9,600,000
    const int LAY1 = CB * CS * CD / 4;    // 64,000
    const int TOT = TOT0 + 10 * LAY1;     // 10,240,000

    for (int i = blockIdx.x * blockDim.x + threadIdx.x; i < TOT;
         i += gridDim.x * blockDim.x) {
        float4 v;
        if (i < TOT0) {
            int layer = i / LAY0;
            int r = i - layer * LAY0;
            int b = r / SLD4;
            int r2 = r - b * SLD4;
            int ld4 = r2 % LD4;
            const float* src = (layer == 0) ? sess_self : (layer == 1) ? emb0 : emb1;
            v = ((const float4*)src)[b * LD4 + ld4];
        } else {
            int j = i - TOT0;
            int layer = j / LAY1;
            int r = j - layer * LAY1;
            int k = layer % 5;
            const float* src = (k == 4) ? T2 : ((k == 1) || (k == 3)) ? T1 : tar_self;
            v = ((const float4*)src)[r];
        }
        out[i] = v;
    }
}

extern "C" void kernel_launch(void* const* d_in, const int* in_sizes, int n_in,
                              void* d_out, int out_size, void* d_ws, size_t ws_size,
                              hipStream_t stream)
{
    const float* sess_self      = (const float*)d_in[0];
    const float* sess_neighbor  = (const float*)d_in[1];
    const float* sess_neighbor2 = (const float*)d_in[2];
    const float* tar_self       = (const float*)d_in[3];
    const float* tar_neighbor   = (const float*)d_in[4];
    const float* w1             = (const float*)d_in[5];  // [2, D, D]
    const float* w2             = (const float*)d_in[6];  // [2, D, 1]
    const float* w3             = (const float*)d_in[7];  // [2, 2D, D]
    const float* w4             = (const float*)d_in[8];  // [2, D, 1]
    float* out = (float*)d_out;
    float* ws  = (float*)d_ws;

    // workspace (floats): emb0 640k | emb1 640k | sn1 7.68M | T1 256k | T2 256k
    // then bf16 weights: w1t 28672 sh, w3t 50176 sh  (total ~38.05 MB)
    float* emb0 = ws;
    float* emb1 = ws + 640000;
    float* sn1  = ws + 1280000;
    float* T1   = ws + 8960000;
    float* T2   = ws + 9216000;
    unsigned short* w1t = (unsigned short*)(ws + 9472000);
    unsigned short* w3t = w1t + 28672;

    prep_weights_kernel<<<308, 256, 0, stream>>>(w1, w3, w1t, w3t);

    // layer 0 session attention: ctx = sess_self
    neigh_mfma_kernel<1><<<800, 256, 0, stream>>>(
        sess_self, sess_neighbor, w1t, w2, emb0, CB * CL);
    // 2-hop aggregation (layer-0 weights): groups = (b,l,n)
    neigh_mfma_kernel<0><<<9600, 256, 0, stream>>>(
        sess_neighbor, sess_neighbor2, w1t, w2, sn1, CB * CL * CN);
    // layer 1 session attention: ctx = emb0, nbr = sn1
    neigh_mfma_kernel<1><<<800, 256, 0, stream>>>(
        emb0, sn1, w1t + 112 * 128, w2 + CD, emb1, CB * CL);
    // target attention layer 0: t = tar_self, sl = emb0[b, l=0, :]
    tar_mfma_kernel<<<320, 256, 0, stream>>>(
        tar_self, emb0, tar_neighbor, w3t, w4, tar_self, T1, CL * CD);
    // target attention layer 1: t = T1, sl = sess_self[b, 0, :]
    tar_mfma_kernel<<<320, 256, 0, stream>>>(
        T1, sess_self, tar_neighbor, w3t + 112 * 224, w4 + CD, tar_self, T2, CL * CD);

    assemble_kernel<<<2048, 256, 0, stream>>>(
        sess_self, emb0, emb1, tar_self, T1, T2, (float4*)out);
}

// Round 3
// 317.734 us; speedup vs baseline: 4.3784x; 1.5708x over previous
//
#include <hip/hip_runtime.h>
#include <cmath>

// Problem dims (fixed)
#define CB 128   // B
#define CL 50    // L
#define CN 12    // N == N2
#define CS 20    // S
#define CM 12    // M
#define CD 100   // D

typedef __attribute__((ext_vector_type(8))) short short8;
typedef __attribute__((ext_vector_type(4))) float f32x4;

__device__ __forceinline__ unsigned short f2bf(float f) {
    unsigned int u = __float_as_uint(f);
    u += 0x7FFFu + ((u >> 16) & 1u);     // round-to-nearest-even
    return (unsigned short)(u >> 16);
}
__device__ __forceinline__ float4 mul4(float4 a, float4 b) {
    return make_float4(a.x * b.x, a.y * b.y, a.z * b.z, a.w * b.w);
}
__device__ __forceinline__ float4 add4(float4 a, float4 b) {
    return make_float4(a.x + b.x, a.y + b.y, a.z + b.z, a.w + b.w);
}
__device__ __forceinline__ short8 pack8(float4 a, float4 b) {
    short8 v;
    v[0] = (short)f2bf(a.x); v[1] = (short)f2bf(a.y);
    v[2] = (short)f2bf(a.z); v[3] = (short)f2bf(a.w);
    v[4] = (short)f2bf(b.x); v[5] = (short)f2bf(b.y);
    v[6] = (short)f2bf(b.z); v[7] = (short)f2bf(b.w);
    return v;
}

// ---------------------------------------------------------------------------
// Weight prep: transpose + pad + bf16-convert.
//   w1t[l][n][k] : n<112, k<128,  = w1[l][k][n] (valid n<100,k<100 else 0)
//   w3t[l][n][k] : n<112, k<224,  = w3[l][k][n] (valid n<100,k<200 else 0)
// ---------------------------------------------------------------------------
__global__ void prep_weights_kernel(const float* __restrict__ w1,
                                    const float* __restrict__ w3,
                                    unsigned short* __restrict__ w1t,
                                    unsigned short* __restrict__ w3t)
{
    int idx = blockIdx.x * 256 + threadIdx.x;
    const int TOT1 = 2 * 112 * 128;   // 28672
    const int TOT3 = 2 * 112 * 224;   // 50176
    if (idx < TOT1) {
        int l = idx / (112 * 128);
        int r = idx - l * (112 * 128);
        int n = r / 128, k = r - (r / 128) * 128;
        float v = (n < CD && k < CD) ? w1[l * CD * CD + k * CD + n] : 0.f;
        w1t[idx] = f2bf(v);
    } else if (idx < TOT1 + TOT3) {
        int j = idx - TOT1;
        int l = j / (112 * 224);
        int r = j - l * (112 * 224);
        int n = r / 224, k = r - (r / 224) * 224;
        float v = (n < CD && k < 2 * CD) ? w3[l * 2 * CD * CD + k * CD + n] : 0.f;
        w3t[j] = f2bf(v);
    }
}

// ---------------------------------------------------------------------------
// Fused neighbor attention via MFMA, A-fragments built in registers.
// 8 groups (128 padded rows) per block; only weights staged in LDS.
// ---------------------------------------------------------------------------
template<int DO_L2>
__global__ __launch_bounds__(256, 4) void neigh_mfma_kernel(
    const float* __restrict__ a_ptr,          // [G, 100]
    const float* __restrict__ c_ptr,          // [G, 12, 100]
    const unsigned short* __restrict__ w1t,   // [112][128] bf16
    const float* __restrict__ w2,             // [100]
    float* __restrict__ outp)                 // [G, 100]
{
    __shared__ __align__(16) unsigned short sB[112 * 128];  // 28 KB, 256B rows
    __shared__ float s_score[128];
    __shared__ float s_att[96];
    __shared__ float s_sq[8][25];
    __shared__ float s_rn[8];

    const int tid = threadIdx.x;
    const int g0 = blockIdx.x * 8;
    const int wave = tid >> 6, lane = tid & 63;
    const int lhi = lane >> 4, llo = lane & 15;

    // ---- stage B (weights, XOR-swizzled; 16 quads/row, 3-bit xor in-row) ----
    for (int i = tid; i < 1792; i += 256) {           // 112 rows x 16 chunks
        int n = i >> 4, kc = i & 15;
        short8 v = *(const short8*)(w1t + n * 128 + kc * 8);
        char* dst = (char*)sB + n * 256 + ((kc ^ (n & 7)) << 4);
        *(short8*)dst = v;
    }

    // ---- A fragments straight from global into regs (overlaps B staging) ----
    short8 af[2][4];
#pragma unroll
    for (int mt = 0; mt < 2; ++mt) {
        const int g = g0 + wave * 2 + mt;
        const int n = (llo < CN) ? llo : 0;           // clamp pad rows
        const float* cp = c_ptr + ((size_t)g * CN + n) * CD;
        const float* ap = a_ptr + (size_t)g * CD;
#pragma unroll
        for (int ks = 0; ks < 4; ++ks) {
            const int k0 = ks * 32 + lhi * 8;
            if (ks < 3) {
                float4 c0 = *(const float4*)(cp + k0);
                float4 c1 = *(const float4*)(cp + k0 + 4);
                float4 a0 = *(const float4*)(ap + k0);
                float4 a1 = *(const float4*)(ap + k0 + 4);
                af[mt][ks] = pack8(mul4(a0, c0), mul4(a1, c1));
            } else if (lhi == 0) {                    // k = 96..103 (partial)
                float4 c0 = *(const float4*)(cp + 96);
                float4 a0 = *(const float4*)(ap + 96);
                float4 z = make_float4(0.f, 0.f, 0.f, 0.f);
                af[mt][ks] = pack8(mul4(a0, c0), z);
            } else {
                af[mt][ks] = (short8){0, 0, 0, 0, 0, 0, 0, 0};
            }
        }
    }
    __syncthreads();

    // ---- MFMA: 2 row-tiles x 7 col-tiles, K = 128 ----
    f32x4 acc[2][7];
#pragma unroll
    for (int mt = 0; mt < 2; ++mt)
#pragma unroll
        for (int nt = 0; nt < 7; ++nt)
            acc[mt][nt] = (f32x4){0.f, 0.f, 0.f, 0.f};

    const char* pB = (const char*)sB;
    const int bxor = llo & 7;
#pragma unroll
    for (int ks = 0; ks < 4; ++ks) {
        const int kbq = ks * 4 + lhi;                 // logical quad 0..15
        short8 bf[7];
#pragma unroll
        for (int nt = 0; nt < 7; ++nt)
            bf[nt] = *(const short8*)(pB + (nt * 16 + llo) * 256 + ((kbq ^ bxor) << 4));
#pragma unroll
        for (int mt = 0; mt < 2; ++mt)
#pragma unroll
            for (int nt = 0; nt < 7; ++nt)
                acc[mt][nt] = __builtin_amdgcn_mfma_f32_16x16x32_bf16(
                    af[mt][ks], bf[nt], acc[mt][nt], 0, 0, 0);
    }

    // ---- scores: leaky + dot w2, 16-lane reduce ----
    float w2v[7];
#pragma unroll
    for (int nt = 0; nt < 7; ++nt) {
        int n = nt * 16 + llo;
        w2v[nt] = (n < CD) ? w2[n] : 0.f;
    }
#pragma unroll
    for (int mt = 0; mt < 2; ++mt) {
        float s[4] = {0.f, 0.f, 0.f, 0.f};
#pragma unroll
        for (int nt = 0; nt < 7; ++nt)
#pragma unroll
            for (int r = 0; r < 4; ++r) {
                float y = acc[mt][nt][r];
                y = (y >= 0.f) ? y : 0.2f * y;
                s[r] = fmaf(y, w2v[nt], s[r]);
            }
#pragma unroll
        for (int off = 1; off < 16; off <<= 1)
#pragma unroll
            for (int r = 0; r < 4; ++r) s[r] += __shfl_xor(s[r], off, 64);
        if (llo == 0) {
            int rowb = wave * 32 + mt * 16 + lhi * 4;
#pragma unroll
            for (int r = 0; r < 4; ++r) s_score[rowb + r] = s[r];
        }
    }
    __syncthreads();

    // ---- parallel softmax: one thread per (group, n) ----
    if (tid < 96) {
        const int g = tid / 12;
        const int n = tid - g * 12;
        const float* sr = s_score + g * 16;
        float mx = -1e30f;
#pragma unroll
        for (int j = 0; j < CN; ++j) mx = fmaxf(mx, sr[j]);
        float sum = 0.f;
#pragma unroll
        for (int j = 0; j < CN; ++j) sum += __expf(sr[j] - mx);
        s_att[tid] = __expf(sr[n] - mx) / sum;
    }
    __syncthreads();

    // ---- weighted sum (fp32 re-read, L2-hot) + optional l2norm + store ----
    const bool act = tid < 200;
    int gl = tid / 25, d4 = tid % 25;
    float4 tot = make_float4(0.f, 0.f, 0.f, 0.f);
    if (act) {
        const float* crow = c_ptr + (size_t)(g0 + gl) * CN * CD + d4 * 4;
#pragma unroll
        for (int n = 0; n < CN; ++n) {
            float4 cv = *(const float4*)(crow + n * CD);
            float at = s_att[gl * CN + n];
            tot.x = fmaf(at, cv.x, tot.x);
            tot.y = fmaf(at, cv.y, tot.y);
            tot.z = fmaf(at, cv.z, tot.z);
            tot.w = fmaf(at, cv.w, tot.w);
        }
    }
    if (DO_L2) {
        if (act) s_sq[gl][d4] = tot.x * tot.x + tot.y * tot.y + tot.z * tot.z + tot.w * tot.w;
        __syncthreads();
        if (tid < 8) {
            float sq = 0.f;
            for (int j = 0; j < 25; ++j) sq += s_sq[tid][j];
            s_rn[tid] = 1.f / fmaxf(sqrtf(sq), 1e-12f);
        }
        __syncthreads();
        if (act) {
            float rn = s_rn[gl];
            tot.x *= rn; tot.y *= rn; tot.z *= rn; tot.w *= rn;
        }
    }
    if (act) *(float4*)(outp + (size_t)(g0 + gl) * CD + d4 * 4) = tot;
}

// ---------------------------------------------------------------------------
// Fused target attention via MFMA, A in registers, K = 200 -> 224.
// sB compact 448B rows; XOR swizzle clamped to 2 bits in last quad-block so it
// stays bijective within the 28-quad (non-pow2) row.
// ---------------------------------------------------------------------------
__device__ __forceinline__ int swzq28(int q, int x) {
    return q ^ ((q < 24) ? x : (x & 3));
}
__device__ __forceinline__ float4 xchunk(const float* __restrict__ tnr,
                                         const float* __restrict__ tv,
                                         const float* __restrict__ slv, int k) {
    if (k < CD)
        return mul4(*(const float4*)(tv + k), *(const float4*)(tnr + k));
    if (k < 2 * CD) {
        int k2 = k - CD;
        return add4(*(const float4*)(slv + k2), *(const float4*)(tnr + k2));
    }
    return make_float4(0.f, 0.f, 0.f, 0.f);
}

__global__ __launch_bounds__(256, 3) void tar_mfma_kernel(
    const float* __restrict__ tvec,           // [2560, 100]
    const float* __restrict__ sl,             // per-b row, stride slStride
    const float* __restrict__ tn,             // [2560, 12, 100]
    const unsigned short* __restrict__ w3t,   // [112][224] bf16
    const float* __restrict__ w4,             // [100]
    const float* __restrict__ tar0,           // [2560, 100]
    float* __restrict__ outp,                 // [2560, 100]
    int slStride)
{
    __shared__ __align__(16) unsigned short sB[112 * 224];  // 49 KB, 448B rows
    __shared__ float s_score[128];
    __shared__ float s_att[96];
    __shared__ float s_sq[8][25];
    __shared__ float s_rn[8];

    const int tid = threadIdx.x;
    const int g0 = blockIdx.x * 8;
    const int wave = tid >> 6, lane = tid & 63;
    const int lhi = lane >> 4, llo = lane & 15;

    // ---- stage B ----
    for (int i = tid; i < 3136; i += 256) {           // 112 rows x 28 chunks
        int n = i / 28, kc = i - (i / 28) * 28;
        short8 v = *(const short8*)(w3t + n * 224 + kc * 8);
        char* dst = (char*)sB + n * 448 + (swzq28(kc, n & 7) << 4);
        *(short8*)dst = v;
    }

    // ---- A fragments in registers ----
    short8 af[2][7];
#pragma unroll
    for (int mt = 0; mt < 2; ++mt) {
        const int g = g0 + wave * 2 + mt;
        const int b = g / CS;
        const int m = (llo < CM) ? llo : 0;
        const float* tnr = tn + ((size_t)g * CM + m) * CD;
        const float* tv = tvec + (size_t)g * CD;
        const float* slv = sl + (size_t)b * slStride;
#pragma unroll
        for (int ks = 0; ks < 7; ++ks) {
            const int k0 = ks * 32 + lhi * 8;
            af[mt][ks] = pack8(xchunk(tnr, tv, slv, k0),
                               xchunk(tnr, tv, slv, k0 + 4));
        }
    }
    __syncthreads();

    // ---- MFMA: K = 224 (7 k-steps) ----
    f32x4 acc[2][7];
#pragma unroll
    for (int mt = 0; mt < 2; ++mt)
#pragma unroll
        for (int nt = 0; nt < 7; ++nt)
            acc[mt][nt] = (f32x4){0.f, 0.f, 0.f, 0.f};

    const char* pB = (const char*)sB;
    const int bxor = llo & 7;
#pragma unroll
    for (int ks = 0; ks < 7; ++ks) {
        const int kbq = ks * 4 + lhi;                 // 0..27
        short8 bf[7];
#pragma unroll
        for (int nt = 0; nt < 7; ++nt)
            bf[nt] = *(const short8*)(pB + (nt * 16 + llo) * 448 + (swzq28(kbq, bxor) << 4));
#pragma unroll
        for (int mt = 0; mt < 2; ++mt)
#pragma unroll
            for (int nt = 0; nt < 7; ++nt)
                acc[mt][nt] = __builtin_amdgcn_mfma_f32_16x16x32_bf16(
                    af[mt][ks], bf[nt], acc[mt][nt], 0, 0, 0);
    }

    // ---- scores: tanh + dot w4, 16-lane reduce ----
    float w4v[7];
#pragma unroll
    for (int nt = 0; nt < 7; ++nt) {
        int n = nt * 16 + llo;
        w4v[nt] = (n < CD) ? w4[n] : 0.f;
    }
#pragma unroll
    for (int mt = 0; mt < 2; ++mt) {
        float s[4] = {0.f, 0.f, 0.f, 0.f};
#pragma unroll
        for (int nt = 0; nt < 7; ++nt)
#pragma unroll
            for (int r = 0; r < 4; ++r)
                s[r] = fmaf(tanhf(acc[mt][nt][r]), w4v[nt], s[r]);
#pragma unroll
        for (int off = 1; off < 16; off <<= 1)
#pragma unroll
            for (int r = 0; r < 4; ++r) s[r] += __shfl_xor(s[r], off, 64);
        if (llo == 0) {
            int rowb = wave * 32 + mt * 16 + lhi * 4;
#pragma unroll
            for (int r = 0; r < 4; ++r) s_score[rowb + r] = s[r];
        }
    }
    __syncthreads();

    if (tid < 96) {
        const int g = tid / 12;
        const int m = tid - g * 12;
        const float* sr = s_score + g * 16;
        float mx = -1e30f;
#pragma unroll
        for (int j = 0; j < CM; ++j) mx = fmaxf(mx, sr[j]);
        float sum = 0.f;
#pragma unroll
        for (int j = 0; j < CM; ++j) sum += __expf(sr[j] - mx);
        s_att[tid] = __expf(sr[m] - mx) / sum;
    }
    __syncthreads();

    const bool act = tid < 200;
    int gl = tid / 25, d4 = tid % 25;
    float4 tot = make_float4(0.f, 0.f, 0.f, 0.f);
    if (act) {
        const float* tnr = tn + (size_t)(g0 + gl) * CM * CD + d4 * 4;
#pragma unroll
        for (int m = 0; m < CM; ++m) {
            float4 cv = *(const float4*)(tnr + m * CD);
            float at = s_att[gl * CM + m];
            tot.x = fmaf(at, cv.x, tot.x);
            tot.y = fmaf(at, cv.y, tot.y);
            tot.z = fmaf(at, cv.z, tot.z);
            tot.w = fmaf(at, cv.w, tot.w);
        }
        float4 t0 = *(const float4*)(tar0 + (size_t)(g0 + gl) * CD + d4 * 4);
        tot.x = (tot.x + t0.x) * 0.5f;
        tot.y = (tot.y + t0.y) * 0.5f;
        tot.z = (tot.z + t0.z) * 0.5f;
        tot.w = (tot.w + t0.w) * 0.5f;
        s_sq[gl][d4] = tot.x * tot.x + tot.y * tot.y + tot.z * tot.z + tot.w * tot.w;
    }
    __syncthreads();
    if (tid < 8) {
        float sq = 0.f;
        for (int j = 0; j < 25; ++j) sq += s_sq[tid][j];
        s_rn[tid] = 1.f / fmaxf(sqrtf(sq), 1e-12f);
    }
    __syncthreads();
    if (act) {
        float rn = s_rn[gl];
        tot.x *= rn; tot.y *= rn; tot.z *= rn;
        tot.w *= rn;
        *(float4*)(outp + (size_t)(g0 + gl) * CD + d4 * 4) = tot;
    }
}

// ---------------------------------------------------------------------------
// Output assembly (unchanged, verified).
// ---------------------------------------------------------------------------
__global__ void assemble_kernel(
    const float* __restrict__ sess_self, const float* __restrict__ emb0,
    const float* __restrict__ emb1, const float* __restrict__ tar_self,
    const float* __restrict__ T1, const float* __restrict__ T2,
    float4* __restrict__ out)
{
    const int LD4 = CL * CD / 4;          // 1250
    const int SLD4 = CS * LD4;            // 25000
    const int LAY0 = CB * SLD4;           // 3,200,000
    const int TOT0 = 3 * LAY0;            // 9,600,000
    const int LAY1 = CB * CS * CD / 4;    // 64,000
    const int TOT = TOT0 + 10 * LAY1;     // 10,240,000

    for (int i = blockIdx.x * blockDim.x + threadIdx.x; i < TOT;
         i += gridDim.x * blockDim.x) {
        float4 v;
        if (i < TOT0) {
            int layer = i / LAY0;
            int r = i - layer * LAY0;
            int b = r / SLD4;
            int r2 = r - b * SLD4;
            int ld4 = r2 % LD4;
            const float* src = (layer == 0) ? sess_self : (layer == 1) ? emb0 : emb1;
            v = ((const float4*)src)[b * LD4 + ld4];
        } else {
            int j = i - TOT0;
            int layer = j / LAY1;
            int r = j - layer * LAY1;
            int k = layer % 5;
            const float* src = (k == 4) ? T2 : ((k == 1) || (k == 3)) ? T1 : tar_self;
            v = ((const float4*)src)[r];
        }
        out[i] = v;
    }
}

extern "C" void kernel_launch(void* const* d_in, const int* in_sizes, int n_in,
                              void* d_out, int out_size, void* d_ws, size_t ws_size,
                              hipStream_t stream)
{
    const float* sess_self      = (const float*)d_in[0];
    const float* sess_neighbor  = (const float*)d_in[1];
    const float* sess_neighbor2 = (const float*)d_in[2];
    const float* tar_self       = (const float*)d_in[3];
    const float* tar_neighbor   = (const float*)d_in[4];
    const float* w1             = (const float*)d_in[5];  // [2, D, D]
    const float* w2             = (const float*)d_in[6];  // [2, D, 1]
    const float* w3             = (const float*)d_in[7];  // [2, 2D, D]
    const float* w4             = (const float*)d_in[8];  // [2, D, 1]
    float* out = (float*)d_out;
    float* ws  = (float*)d_ws;

    // workspace (floats): emb0 640k | emb1 640k | sn1 7.68M | T1 256k | T2 256k
    // then bf16 weights: w1t 28672 sh, w3t 50176 sh
    float* emb0 = ws;
    float* emb1 = ws + 640000;
    float* sn1  = ws + 1280000;
    float* T1   = ws + 8960000;
    float* T2   = ws + 9216000;
    unsigned short* w1t = (unsigned short*)(ws + 9472000);
    unsigned short* w3t = w1t + 28672;

    prep_weights_kernel<<<308, 256, 0, stream>>>(w1, w3, w1t, w3t);

    // layer 0 session attention: ctx = sess_self
    neigh_mfma_kernel<1><<<800, 256, 0, stream>>>(
        sess_self, sess_neighbor, w1t, w2, emb0);
    // 2-hop aggregation (layer-0 weights): groups = (b,l,n)
    neigh_mfma_kernel<0><<<9600, 256, 0, stream>>>(
        sess_neighbor, sess_neighbor2, w1t, w2, sn1);
    // layer 1 session attention: ctx = emb0, nbr = sn1
    neigh_mfma_kernel<1><<<800, 256, 0, stream>>>(
        emb0, sn1, w1t + 112 * 128, w2 + CD, emb1);
    // target attention layer 0: t = tar_self, sl = emb0[b, l=0, :]
    tar_mfma_kernel<<<320, 256, 0, stream>>>(
        tar_self, emb0, tar_neighbor, w3t, w4, tar_self, T1, CL * CD);
    // target attention layer 1: t = T1, sl = sess_self[b, 0, :]
    tar_mfma_kernel<<<320, 256, 0, stream>>>(
        T1, sess_self, tar_neighbor, w3t + 112 * 224, w4 + CD, tar_self, T2, CL * CD);

    assemble_kernel<<<2048, 256, 0, stream>>>(
        sess_self, emb0, emb1, tar_self, T1, T2, (float4*)out);
}